// Round 8
// baseline (104.846 us; speedup 1.0000x reference)
//
#include <hip/hip_runtime.h>
#include <hip/hip_bf16.h>

typedef __bf16 bf16x4 __attribute__((ext_vector_type(4)));
typedef __bf16 bf16x8 __attribute__((ext_vector_type(8)));
typedef float  f32x4  __attribute__((ext_vector_type(4)));
typedef float  f32x16 __attribute__((ext_vector_type(16)));

#define H_  8
#define D_  32
#define L_  4096
#define S_  4096
#define BM  64
#define BM4 128
#define BN  64
#define NSPLIT 4

static __device__ __forceinline__ f32x4 mfma_k16(bf16x4 a, bf16x4 b, f32x4 c) {
#if __has_builtin(__builtin_amdgcn_mfma_f32_16x16x16_bf16)
    return __builtin_amdgcn_mfma_f32_16x16x16_bf16(a, b, c, 0, 0, 0);
#else
    asm("v_mfma_f32_16x16x16_bf16 %0, %1, %2, %0" : "+v"(c) : "v"(a), "v"(b));
    return c;
#endif
}

// ---------- merged pre-pass: K convert + V transpose (one launch) ----------
__global__ __launch_bounds__(256)
void prep_kv(const float* __restrict__ kk, const float* __restrict__ v,
             __bf16* __restrict__ kb, __bf16* __restrict__ vt)
{
    const int h  = blockIdx.y;
    const int s0 = blockIdx.x * 64;
    const int sr = threadIdx.x >> 2, dseg = (threadIdx.x & 3) * 8;
    // K: straight convert [s][h][d] -> [h][s][d]
    {
        const float* ip = kk + (((size_t)(s0 + sr) * H_ + h) * D_ + dseg);
        float4 a = *(const float4*)ip, b = *(const float4*)(ip + 4);
        bf16x8 o;
        o[0]=(__bf16)a.x; o[1]=(__bf16)a.y; o[2]=(__bf16)a.z; o[3]=(__bf16)a.w;
        o[4]=(__bf16)b.x; o[5]=(__bf16)b.y; o[6]=(__bf16)b.z; o[7]=(__bf16)b.w;
        *(bf16x8*)(kb + ((size_t)h * S_ + s0 + sr) * D_ + dseg) = o;
    }
    // V: transpose [s][h][d] -> [h][d][s] via LDS
    __shared__ __bf16 T[D_][72];
    {
        const float* ip = v + (((size_t)(s0 + sr) * H_ + h) * D_ + dseg);
        float4 a = *(const float4*)ip, b = *(const float4*)(ip + 4);
        float vv[8] = {a.x, a.y, a.z, a.w, b.x, b.y, b.z, b.w};
#pragma unroll
        for (int j = 0; j < 8; ++j) T[dseg + j][sr] = (__bf16)vv[j];
    }
    __syncthreads();
    const int d = threadIdx.x >> 3, so = (threadIdx.x & 7) * 8;
    bf16x8 o = *(const bf16x8*)(&T[d][so]);
    *(bf16x8*)(vt + ((size_t)h * D_ + d) * S_ + s0 + so) = o;
}

// ---------- main kernel v7: v5 (best-measured) + per-u exp/cvt interleave ----------
// v5 halved LDS reads + removed scatter-writes but only gained 1us: estimated
// ~125 VGPR at the (256,4) cap of 128 -> spill/pinch ate the win. v7 = v5 with
// p-liveness 16->8 (exp/cvt/PV interleaved per u-slot), est ~-8 VGPR. Minimal
// diff vs the best baseline so the A/B isolates the register-pressure theory.
__global__ __launch_bounds__(256, 4)
void fattn_v7(const __bf16* __restrict__ kb, const __bf16* __restrict__ vtg,
              const float* __restrict__ q, float* __restrict__ num,
              float* __restrict__ den, int schunk)
{
    const int qt = blockIdx.x, h = blockIdx.y, sp = blockIdx.z;
    const int tid = threadIdx.x, wave = tid >> 6, lane = tid & 63;
    const int ln = lane & 31, hl = lane >> 5;
    const int wq = wave >> 1, ws = wave & 1;

    __shared__ __align__(16) __bf16 Ks[2][64][40];   // 80B rows: conflict-free b128
    __shared__ __align__(16) __bf16 Vt[2][D_][72];   // 144B rows: conflict-free b128

    const float cs = 0.17677669529663687f * 1.4426950408889634f; // log2e/sqrt(32)

    // Q fragments for the wave's two 32-q subblocks
    bf16x8 qf[2][2];
#pragma unroll
    for (int qh = 0; qh < 2; ++qh) {
        const int qn = qt * BM4 + wq * 64 + qh * 32 + ln;
        const float* qp = q + ((size_t)qn * H_ + h) * D_ + hl * 8;
        float4 a = *(const float4*)qp,        b2 = *(const float4*)(qp + 4);
        float4 c = *(const float4*)(qp + 16), d2 = *(const float4*)(qp + 20);
        qf[qh][0][0]=(__bf16)(a.x*cs);  qf[qh][0][1]=(__bf16)(a.y*cs);
        qf[qh][0][2]=(__bf16)(a.z*cs);  qf[qh][0][3]=(__bf16)(a.w*cs);
        qf[qh][0][4]=(__bf16)(b2.x*cs); qf[qh][0][5]=(__bf16)(b2.y*cs);
        qf[qh][0][6]=(__bf16)(b2.z*cs); qf[qh][0][7]=(__bf16)(b2.w*cs);
        qf[qh][1][0]=(__bf16)(c.x*cs);  qf[qh][1][1]=(__bf16)(c.y*cs);
        qf[qh][1][2]=(__bf16)(c.z*cs);  qf[qh][1][3]=(__bf16)(c.w*cs);
        qf[qh][1][4]=(__bf16)(d2.x*cs); qf[qh][1][5]=(__bf16)(d2.y*cs);
        qf[qh][1][6]=(__bf16)(d2.z*cs); qf[qh][1][7]=(__bf16)(d2.w*cs);
    }

    f32x16 o[2];
    o[0] = (f32x16){0,0,0,0,0,0,0,0,0,0,0,0,0,0,0,0};
    o[1] = (f32x16){0,0,0,0,0,0,0,0,0,0,0,0,0,0,0,0};
    const f32x16 z16 = {0,0,0,0,0,0,0,0,0,0,0,0,0,0,0,0};
    f32x4 accl[2];
    accl[0] = (f32x4){0,0,0,0};
    accl[1] = (f32x4){0,0,0,0};

    // staging indices (256 threads cover 64x32 K-tile and 32x64 Vt-tile)
    const int srow = tid >> 2, kseg = (tid & 3) * 8;
    const int vd   = tid >> 3, vso  = (tid & 7) * 8;

    const int sbeg = sp * schunk;
    const int T = schunk / BN;

    const __bf16* kptr = kb  + ((size_t)h * S_ + sbeg + srow) * D_ + kseg;
    const __bf16* vptr = vtg + ((size_t)h * D_ + vd) * S_ + sbeg + vso;

    bf16x8 kf = *(const bf16x8*)kptr;
    bf16x8 vf = *(const bf16x8*)vptr;
    bf16x8 kn = kf, vn = vf;

    for (int t = 0; t < T; ++t) {
        const int b = t & 1;
        *(bf16x8*)(&Ks[b][srow][kseg]) = kf;
        *(bf16x8*)(&Vt[b][vd][vso])    = vf;
        if (t + 1 < T) {
            kn = *(const bf16x8*)(kptr + (size_t)(t + 1) * BN * D_);
            vn = *(const bf16x8*)(vptr + (t + 1) * BN);
        }
        __syncthreads();   // single barrier per tile

        // wave's K frags (its 32-s half), shared across both q-subblocks
        bf16x8 ka0 = *(const bf16x8*)(&Ks[b][ws * 32 + ln][hl * 8]);
        bf16x8 ka1 = *(const bf16x8*)(&Ks[b][ws * 32 + ln][16 + hl * 8]);
        // wave's V frags (its 32-s half), hoisted: no qh dependence
        bf16x8 va0 = *(const bf16x8*)(&Vt[b][ln][ws * 32 + hl * 8]);
        bf16x8 va1 = *(const bf16x8*)(&Vt[b][ln][ws * 32 + 16 + hl * 8]);

#pragma unroll
        for (int qh = 0; qh < 2; ++qh) {
            f32x16 st = __builtin_amdgcn_mfma_f32_32x32x16_bf16(ka0, qf[qh][0], z16, 0, 0, 0);
            st = __builtin_amdgcn_mfma_f32_32x32x16_bf16(ka1, qf[qh][1], st, 0, 0, 0);
#pragma unroll
            for (int u = 0; u < 2; ++u) {
                float p[8];
#pragma unroll
                for (int r = 0; r < 8; ++r) p[r] = __builtin_amdgcn_exp2f(st[u*8 + r]);
                accl[qh][u*2]     += p[0] + p[1] + p[2] + p[3];
                accl[qh][u*2 + 1] += p[4] + p[5] + p[6] + p[7];
                unsigned A, B, C, D;
                asm("v_cvt_pk_bf16_f32 %0, %1, %2" : "=v"(A) : "v"(p[0]), "v"(p[1]));
                asm("v_cvt_pk_bf16_f32 %0, %1, %2" : "=v"(B) : "v"(p[2]), "v"(p[3]));
                asm("v_cvt_pk_bf16_f32 %0, %1, %2" : "=v"(C) : "v"(p[4]), "v"(p[5]));
                asm("v_cvt_pk_bf16_f32 %0, %1, %2" : "=v"(D) : "v"(p[6]), "v"(p[7]));
                asm("v_permlane32_swap_b32 %0, %1" : "+v"(A), "+v"(C));
                asm("v_permlane32_swap_b32 %0, %1" : "+v"(B), "+v"(D));
                union { unsigned w[4]; bf16x8 f; } pb;
                pb.w[0] = A; pb.w[1] = B; pb.w[2] = C; pb.w[3] = D;
                o[qh] = __builtin_amdgcn_mfma_f32_32x32x16_bf16(u ? va1 : va0, pb.f, o[qh], 0, 0, 0);
            }
        }
        kf = kn; vf = vn;
    }

    // combine per-wave denominator partials (within s-half)
    float dsum[2];
#pragma unroll
    for (int qh = 0; qh < 2; ++qh) {
        float s4 = accl[qh][0] + accl[qh][1] + accl[qh][2] + accl[qh][3];
        s4 += __shfl_xor(s4, 32, 64);
        dsum[qh] = s4;
    }

    // s-half reduction: ws=1 waves dump O/den into (now-dead) LDS buffers;
    // ws=0 waves add and write out. wq=0 -> Ks region, wq=1 -> Vt region.
    __syncthreads();
    float* rb = (wq == 0) ? (float*)&Ks[0][0][0] : (float*)&Vt[0][0][0];
    if (ws == 1) {
#pragma unroll
        for (int qh = 0; qh < 2; ++qh) {
#pragma unroll
            for (int r = 0; r < 16; ++r)
                rb[(qh * 16 + r) * 64 + lane] = o[qh][r];
            rb[2048 + qh * 64 + lane] = dsum[qh];
        }
    }
    __syncthreads();
    if (ws == 0) {
#pragma unroll
        for (int qh = 0; qh < 2; ++qh) {
#pragma unroll
            for (int r = 0; r < 16; ++r)
                o[qh][r] += rb[(qh * 16 + r) * 64 + lane];
            dsum[qh] += rb[2048 + qh * 64 + lane];
            const int qn = qt * BM4 + wq * 64 + qh * 32 + ln;
            float* pr = num + (((size_t)(sp * H_ + h) * L_ + qn) << 5);
            f32x4 w0 = {o[qh][0],  o[qh][1],  o[qh][2],  o[qh][3]};
            f32x4 w1 = {o[qh][4],  o[qh][5],  o[qh][6],  o[qh][7]};
            f32x4 w2 = {o[qh][8],  o[qh][9],  o[qh][10], o[qh][11]};
            f32x4 w3 = {o[qh][12], o[qh][13], o[qh][14], o[qh][15]};
            *(f32x4*)(pr      + hl * 4) = w0;
            *(f32x4*)(pr + 8  + hl * 4) = w1;
            *(f32x4*)(pr + 16 + hl * 4) = w2;
            *(f32x4*)(pr + 24 + hl * 4) = w3;
            if (hl == 0) den[(size_t)(sp * H_ + h) * L_ + qn] = dsum[qh];
        }
    }
}

// ---------- v1 kernel kept verbatim as fallback (small-workspace paths) ----------
template<bool DIRECT>
__global__ __launch_bounds__(256, 6)
void fattn_main(const float* __restrict__ q, const float* __restrict__ kk,
                const float* __restrict__ v, float* __restrict__ num,
                float* __restrict__ den, float* __restrict__ out, int schunk)
{
    const int qt = blockIdx.x, h = blockIdx.y, sp = blockIdx.z;
    const int tid = threadIdx.x, wave = tid >> 6, lane = tid & 63;
    const int col = lane & 15, quad = lane >> 4;

    __shared__ __align__(16) __bf16 Ks[2][BN][40];
    __shared__ __align__(16) __bf16 Vt[2][D_][72];

    const float cs = 0.17677669529663687f * 1.4426950408889634f;

    const int qn = qt * BM + wave * 16 + col;
    bf16x8 qb;
    {
        const float* qp = q + ((size_t)qn * H_ + h) * D_ + quad * 8;
        float4 q0 = *(const float4*)qp;
        float4 q1 = *(const float4*)(qp + 4);
        qb[0]=(__bf16)(q0.x*cs); qb[1]=(__bf16)(q0.y*cs);
        qb[2]=(__bf16)(q0.z*cs); qb[3]=(__bf16)(q0.w*cs);
        qb[4]=(__bf16)(q1.x*cs); qb[5]=(__bf16)(q1.y*cs);
        qb[6]=(__bf16)(q1.z*cs); qb[7]=(__bf16)(q1.w*cs);
    }

    f32x4 o0 = {0,0,0,0}, o1 = {0,0,0,0}, accl = {0,0,0,0};
    const f32x4 zc = {0,0,0,0};
    const bf16x4 ones = {(__bf16)1.f, (__bf16)1.f, (__bf16)1.f, (__bf16)1.f};

    const int srow = tid >> 2;
    const int g    = tid & 3;
    const int dseg = g * 8;
    const int vcol = (srow + 16 * g) & 63;
    const int rot0 = (col >> 3) << 4;

    const int sbeg = sp * schunk;
    const int T = schunk / BN;

    float4 kf0, kf1, vf0, vf1;
    {
        const size_t goff = ((size_t)(sbeg + srow) * H_ + h) * D_ + dseg;
        kf0 = *(const float4*)(kk + goff);
        kf1 = *(const float4*)(kk + goff + 4);
        vf0 = *(const float4*)(v + goff);
        vf1 = *(const float4*)(v + goff + 4);
    }
    float4 kn0 = kf0, kn1 = kf1, vn0 = vf0, vn1 = vf1;

    for (int t = 0; t < T; ++t) {
        const int b = t & 1;
        {
            bf16x8 kb;
            kb[0]=(__bf16)kf0.x; kb[1]=(__bf16)kf0.y; kb[2]=(__bf16)kf0.z; kb[3]=(__bf16)kf0.w;
            kb[4]=(__bf16)kf1.x; kb[5]=(__bf16)kf1.y; kb[6]=(__bf16)kf1.z; kb[7]=(__bf16)kf1.w;
            *(bf16x8*)(&Ks[b][srow][dseg]) = kb;
            float vv[8] = {vf0.x, vf0.y, vf0.z, vf0.w, vf1.x, vf1.y, vf1.z, vf1.w};
#pragma unroll
            for (int j = 0; j < 8; ++j)
                Vt[b][dseg + j][vcol] = (__bf16)vv[j];
        }
        if (t + 1 < T) {
            const size_t goff = ((size_t)(sbeg + (t+1)*BN + srow) * H_ + h) * D_ + dseg;
            kn0 = *(const float4*)(kk + goff);
            kn1 = *(const float4*)(kk + goff + 4);
            vn0 = *(const float4*)(v + goff);
            vn1 = *(const float4*)(v + goff + 4);
        }
        __syncthreads();

#pragma unroll
        for (int sb = 0; sb < 4; ++sb) {
            bf16x8 ka = *(const bf16x8*)(&Ks[b][sb * 16 + col][quad * 8]);
            f32x4 st = __builtin_amdgcn_mfma_f32_16x16x32_bf16(ka, qb, zc, 0, 0, 0);
            bf16x4 pb;
#pragma unroll
            for (int r = 0; r < 4; ++r)
                pb[r] = (__bf16)__builtin_amdgcn_exp2f(st[r]);
            const int sc  = sb * 16 + quad * 4;
            bf16x4 va0 = *(const bf16x4*)(&Vt[b][col     ][(sc + rot0)      & 63]);
            bf16x4 va1 = *(const bf16x4*)(&Vt[b][col + 16][(sc + rot0 + 32) & 63]);
            o0   = mfma_k16(va0,  pb, o0);
            o1   = mfma_k16(va1,  pb, o1);
            accl = mfma_k16(ones, pb, accl);
        }
        kf0 = kn0; kf1 = kn1; vf0 = vn0; vf1 = vn1;
    }

    if (DIRECT) {
        const float inv = 1.f / accl[0];
        float* op = out + ((size_t)qn * H_ + h) * D_;
        f32x4 r0 = {o0[0]*inv, o0[1]*inv, o0[2]*inv, o0[3]*inv};
        f32x4 r1 = {o1[0]*inv, o1[1]*inv, o1[2]*inv, o1[3]*inv};
        *(f32x4*)(op + quad * 4)      = r0;
        *(f32x4*)(op + 16 + quad * 4) = r1;
    } else {
        float* pr = num + (((size_t)(sp * H_ + h) * L_ + qn) << 5);
        *(f32x4*)(pr + quad * 4)      = o0;
        *(f32x4*)(pr + 16 + quad * 4) = o1;
        if (quad == 0) den[(size_t)(sp * H_ + h) * L_ + qn] = accl[0];
    }
}

__global__ __launch_bounds__(256)
void fattn_combine(const float* __restrict__ num, const float* __restrict__ den,
                   float* __restrict__ out)
{
    const int i  = blockIdx.x * 256 + threadIdx.x;
    const int d4 = (i & 7) * 4;
    const int h  = (i >> 3) & 7;
    const int l  = i >> 6;
    f32x4 acc = {0,0,0,0};
    float dn = 0.f;
    for (int sp = 0; sp < NSPLIT; ++sp) {
        const float* pr = num + (((size_t)(sp * H_ + h) * L_ + l) << 5) + d4;
        f32x4 t = *(const f32x4*)pr;
        acc[0] += t[0]; acc[1] += t[1]; acc[2] += t[2]; acc[3] += t[3];
        dn += den[(size_t)(sp * H_ + h) * L_ + l];
    }
    const float inv = 1.f / dn;
    f32x4 r = {acc[0]*inv, acc[1]*inv, acc[2]*inv, acc[3]*inv};
    *(f32x4*)(out + ((size_t)l * H_ + h) * D_ + d4) = r;
}

extern "C" void kernel_launch(void* const* d_in, const int* in_sizes, int n_in,
                              void* d_out, int out_size, void* d_ws, size_t ws_size,
                              hipStream_t stream) {
    const float* q = (const float*)d_in[0];
    const float* k = (const float*)d_in[1];
    const float* v = (const float*)d_in[2];
    float* out = (float*)d_out;
    const size_t nnum = (size_t)NSPLIT * H_ * L_ * 32;
    const size_t nden = (size_t)NSPLIT * H_ * L_;
    const size_t nkv  = (size_t)H_ * S_ * D_;              // bf16 elements per tensor
    const size_t need_v7 = (nnum + nden) * sizeof(float) + 2 * nkv * sizeof(__bf16);
    if (ws_size >= need_v7) {
        float* num = (float*)d_ws;
        float* den = num + nnum;
        __bf16* kbp = (__bf16*)(den + nden);
        __bf16* vtp = kbp + nkv;
        prep_kv<<<dim3(S_ / 64, H_), 256, 0, stream>>>(k, v, kbp, vtp);
        fattn_v7<<<dim3(L_ / BM4, H_, NSPLIT), 256, 0, stream>>>(
            kbp, vtp, q, num, den, S_ / NSPLIT);
        fattn_combine<<<dim3((L_ * H_ * D_ / 4) / 256), 256, 0, stream>>>(num, den, out);
    } else if (ws_size >= (nnum + nden) * sizeof(float)) {
        float* num = (float*)d_ws;
        float* den = num + nnum;
        fattn_main<false><<<dim3(L_ / BM, H_, NSPLIT), 256, 0, stream>>>(
            q, k, v, num, den, out, S_ / NSPLIT);
        fattn_combine<<<dim3((L_ * H_ * D_ / 4) / 256), 256, 0, stream>>>(num, den, out);
    } else {
        fattn_main<true><<<dim3(L_ / BM, H_, 1), 256, 0, stream>>>(
            q, k, v, nullptr, nullptr, out, S_);
    }
}